// Round 14
// baseline (174.979 us; speedup 1.0000x reference)
//
#include <hip/hip_runtime.h>
#include <hip/hip_bf16.h>
#include <cstdint>
#include <cstddef>

#define EMB_K   1024
#define EMB_C   256
#define HWB     4096        // 64*64 per batch
#define NPIX    65536       // 16*4096

typedef __bf16 bf16x8 __attribute__((ext_vector_type(8)));
typedef float  f32x4  __attribute__((ext_vector_type(4)));

__device__ __forceinline__ unsigned short bf16bits(float v) {
  __hip_bfloat16 h = __float2bfloat16(v);
  return __builtin_bit_cast(unsigned short, h);
}

// ---- emb -> bf16 row-major + fp32 norms; zero loss ----
__global__ void k_emb(const float* __restrict__ emb, unsigned short* __restrict__ emb_bf,
                      float* __restrict__ enorm, float* __restrict__ loss) {
  int k = blockIdx.x;      // 0..1023
  int c = threadIdx.x;     // 0..255
  if (k == 0 && c == 0) *loss = 0.f;
  float v = emb[(size_t)k * EMB_C + c];
  emb_bf[(size_t)k * EMB_C + c] = bf16bits(v);
  float s = v * v;
  for (int m = 32; m; m >>= 1) s += __shfl_down(s, m, 64);
  __shared__ float red[4];
  int lane = c & 63, w = c >> 6;
  if (lane == 0) red[w] = s;
  __syncthreads();
  if (c == 0) enorm[k] = red[0] + red[1] + red[2] + red[3];
}

// ================= transpose kernel: x -> A (FRAGMENT-ORDERED bf16) =================
// 1024 blocks x 512 thr, 32.25KB LDS -> 4 blocks/CU = 32 waves/CU. Block owns
// 64 n. R13's direct fragment-scatter wrote 16B/lane to 64 distinct lines (64
// txns/instr, 4x write-request amplification -> 27us). Fix: stage the 32KB
// fragment-ordered tile in LDS (XOR quad<<1 for 8-way bank spread), then dump
// as LINEAR 1KB/wave uint4 stores. Reads unchanged (16B/lane coalesced).
__global__ __launch_bounds__(512) void
k_tr(const float* __restrict__ x, unsigned short* __restrict__ A,
     float* __restrict__ xn_g) {
  __shared__ uint4 tile[2048];               // 32KB, fragment-order chunks
  __shared__ float xn_l[64];
  int t  = threadIdx.x;
  int n0 = blockIdx.x * 64;
  int b  = n0 >> 12, hw0 = n0 & 4095;
  int hwq = t & 15, c8 = t >> 4;             // hwq: 4-n quad; c8 0..31 (8 c)
  if (t < 64) xn_l[t] = 0.f;
  __syncthreads();
  const float* xp = x + (size_t)b * (EMB_C * HWB) + hw0 + hwq * 4;
  float xn[4] = {0.f, 0.f, 0.f, 0.f};
  unsigned pk[4][4] = {};
#pragma unroll
  for (int j = 0; j < 8; ++j) {              // c = c8*8 + j
    f32x4 v = *(const f32x4*)(xp + (size_t)(c8 * 8 + j) * HWB);  // 16B/lane
#pragma unroll
    for (int m = 0; m < 4; ++m) {
      xn[m] += v[m] * v[m];
      pk[m][j >> 1] |= (unsigned)bf16bits(v[m]) << ((j & 1) * 16);
    }
  }
  int s = c8 >> 2, quad = c8 & 3;
#pragma unroll
  for (int m = 0; m < 4; ++m) {
    int nl = hwq * 4 + m;                    // n-local 0..63
    int i = nl >> 4, lr = nl & 15;
    int local = (i * 8 + s) * 64 + quad * 16 + lr;   // fragment-order chunk
    tile[local ^ (quad << 1)] = *(const uint4*)pk[m];  // XOR: 8-way bank spread
    atomicAdd(&xn_l[nl], xn[m]);
  }
  __syncthreads();
  if (t < 64) xn_g[n0 + t] = xn_l[t];
  // dump: chunk d holds data-for-local l = d ^ (((d>>4)&3)<<1) (XOR involution;
  // bits 4-5 = quad unchanged). Wave covers 64 consecutive d -> 1KB coalesced.
  int blk = n0 >> 8, g = (n0 >> 6) & 3;
  uint4* dst = (uint4*)A + (size_t)blk * 8192 + g * 2048;
#pragma unroll
  for (int q = 0; q < 4; ++q) {
    int d = q * 512 + t;
    dst[d] = tile[d ^ (((d >> 4) & 3) << 1)];
  }
}

// ---- staging: 32 rows x 256c bf16 = 16KB, XOR-swizzled 16B chunks, glds ----
// 512-thread: 1024 chunks, 2 per thread (2 vmcnt units per stage)
__device__ __forceinline__ void stage32(const unsigned short* __restrict__ rows,
                                        unsigned char* buf, int t) {
#pragma unroll
  for (int j = 0; j < 2; ++j) {
    int d = j * 512 + t;             // linear dest chunk 0..1023
    int r = d >> 5;                  // row 0..31
    int slot = d & 31;
    int c16 = ((slot >> 3) << 3) | ((slot & 7) ^ (r & 7));
    const unsigned short* src = rows + (size_t)r * EMB_C + c16 * 8;
    __builtin_amdgcn_global_load_lds(
        (const __attribute__((address_space(1))) void*)src,
        (__attribute__((address_space(3))) void*)(buf + (unsigned)(j * 8192 + (t >> 6) * 1024)),
        16, 0, 0);
  }
}

// ================= main kernel: GEMM + argmin + loss =================
// R13's body (43us) with 32-row B tiles: 4 bufs x 16KB -> 70KB LDS -> 2
// blocks/CU (4 waves/SIMD). R13 at 1 block/CU had ~17us of unhidden
// dependency/barrier stall (busy 26us vs dur 43); a co-resident block fills
// those stalls. Same counted-vmcnt depth-3 rotation, peel 4/2/0 (2-chunk
// stages). af from fragment-ordered A: 32 coalesced 1KB reads, no prologue.
// LDS: [0,64K) bufs 4x16KB | cjl 4K | keys 1K | xn 1K | red
#define LDS_BYTES 71744

__global__ __launch_bounds__(512) void
k_main(const unsigned short* __restrict__ A, const unsigned short* __restrict__ embbf,
       const float* __restrict__ enorm, const float* __restrict__ xn_g,
       unsigned* __restrict__ keys_g, float* __restrict__ loss) {
  extern __shared__ char smem[];
  float*    cjl    = (float*)(smem + 65536);           // 1024 f32
  unsigned* keys_l = (unsigned*)(smem + 69632);        // 256 u32
  float*    xn_l   = (float*)(smem + 70656);           // 256 f32
  float*    red    = (float*)(smem + 71680);           // 16 f32

  int n0 = blockIdx.x * 256;
  int t = threadIdx.x, w = t >> 6, lane = t & 63;
  int quad = lane >> 4, lr = lane & 15;
  int g  = w >> 1;       // n-group 0..3 (64 n)
  int h2 = w & 1;        // k-half (16 k of each 32k tile)

  // B(0)/B(1) staged early: latency hides under af load + init
  stage32(embbf,               (unsigned char*)smem,         t);
  stage32(embbf + 32 * EMB_C,  (unsigned char*)smem + 16384, t);

  if (t < 256) { keys_l[t] = 0u; xn_l[t] = xn_g[n0 + t]; }
  for (int i = t; i < 1024; i += 512) cjl[i] = 0.375f - 0.5f * enorm[i];

  // ---- af: direct coalesced loads from fragment-ordered A ----
  bf16x8 af[4][8];
  const uint4* Ab = (const uint4*)A + (size_t)blockIdx.x * 8192;
#pragma unroll
  for (int i = 0; i < 4; ++i)
#pragma unroll
    for (int s = 0; s < 8; ++s) {
      uint4 q = Ab[((g * 4 + i) * 8 + s) * 64 + lane];   // 1KB/wave coalesced
      af[i][s] = __builtin_bit_cast(bf16x8, q);
    }
  __syncthreads();   // LDS init visible; B(0)/B(1) glds drained

  // ---- K-loop: 32 tiles of 32 k; 4-buf rotation, 1 barrier + counted vmcnt ----
  unsigned best[4][4] = {};
  for (int kt = 0; kt < 32; ++kt) {
    if (kt < 30)
      stage32(embbf + (size_t)(kt + 2) * 32 * EMB_C,
              (unsigned char*)smem + (((kt + 2) & 3) << 14), t);
    // outstanding stages: kt,kt+1,kt+2 = 6 chunks -> wait oldest stage (2 each)
    if (kt < 30)       asm volatile("s_waitcnt vmcnt(4)" ::: "memory");
    else if (kt == 30) asm volatile("s_waitcnt vmcnt(2)" ::: "memory");
    else               asm volatile("s_waitcnt vmcnt(0)" ::: "memory");
    __builtin_amdgcn_s_barrier();              // all waves' stage(kt) landed
    __builtin_amdgcn_sched_barrier(0);         // no LDS-read hoist above
    const unsigned char* srcB = (const unsigned char*)smem + ((kt & 3) << 14);
    int k = kt * 32 + h2 * 16 + lr;
    float cj = cjl[k];
    unsigned kp = 1023u - (unsigned)k;
    f32x4 acc[4] = {};
#pragma unroll
    for (int s = 0; s < 8; ++s) {
      int cc = s * 4 + quad;
      int pos = ((cc >> 3) << 3) | ((cc & 7) ^ (lr & 7));   // rB&7 == lr&7
      bf16x8 bf = *(const bf16x8*)(srcB + (h2 * 16 + lr) * 512 + pos * 16);
#pragma unroll
      for (int i = 0; i < 4; ++i)
        acc[i] = __builtin_amdgcn_mfma_f32_16x16x32_bf16(af[i][s], bf, acc[i], 0, 0, 0);
    }
    // fold argmin keys: f = dot + 0.375 - 0.5||e||^2 in (0.04,0.71) -> positive
    // float u32-order-correct; low 10 mantissa bits carry (1023-k).
#pragma unroll
    for (int i = 0; i < 4; ++i)
#pragma unroll
      for (int r = 0; r < 4; ++r) {
        float f = acc[i][r] + cj;
        unsigned key = (__float_as_uint(f) & 0xFFFFFC00u) | kp;
        best[i][r] = best[i][r] > key ? best[i][r] : key;
      }
  }
  __syncthreads();   // k-loop complete before keys_l atomics phase

  // ---- combine keys across k-lanes; k-halves via LDS atomicMax ----
#pragma unroll
  for (int i = 0; i < 4; ++i)
#pragma unroll
    for (int r = 0; r < 4; ++r) {
      unsigned v = best[i][r];
#pragma unroll
      for (int m = 1; m < 16; m <<= 1) {
        unsigned o = (unsigned)__shfl_xor((int)v, m, 64);
        v = v > o ? v : o;
      }
      if (lr == 0) atomicMax(&keys_l[g * 64 + i * 16 + quad * 4 + r], v);
    }
  __syncthreads();

  // ---- keys export + loss partial: d2 = ||x||^2 + 0.75 - 2*f_hat ----
  if (t < 256) {
    unsigned key = keys_l[t];
    keys_g[n0 + t] = key;
    float fh = __uint_as_float(key & 0xFFFFFC00u);
    float lsum = xn_l[t] + 0.75f - 2.0f * fh;
    for (int m = 32; m; m >>= 1) lsum += __shfl_down(lsum, m, 64);
    if (lane == 0) red[w] = lsum;
  }
  __syncthreads();
  if (t == 0)
    atomicAdd(loss, red[0] + red[1] + red[2] + red[3]);   // device-scope
}

// ================= output kernel: gather + transpose + store =================
// 2048 blocks x 256 thr, 16.6KB LDS -> 8 blocks/CU = 32 waves/CU (proven R12:
// ~5.3 TB/s). Stride-65 LDS tile conflict-free both directions; 256B/wave
// scalar-row stores alignment-proof vs out+1. Loss finalize here.
__global__ __launch_bounds__(256) void
k_out(const float* __restrict__ emb, const unsigned* __restrict__ keys_g,
      const float* __restrict__ loss, float* __restrict__ out) {
  __shared__ float tile[64 * 65];            // 16.25 KB
  __shared__ int   idx_l[64];
  int e  = blockIdx.x;
  int nt = e >> 1, cH = e & 1;
  int n0 = nt * 64;
  int b  = n0 >> 12, hw0 = n0 & 4095;
  int t = threadIdx.x, w = t >> 6, lane = t & 63;
  if (e == 0 && t == 0)
    out[0] = 1.0625f * (*loss) / 16777216.0f;
  if (t < 64) idx_l[t] = 1023 - (int)(keys_g[n0 + t] & 1023u);
  __syncthreads();
  int nn = t >> 2, ch = t & 3;               // 4 threads per n
  const float* er = emb + (size_t)idx_l[nn] * EMB_C + cH * 128;
  float* ob = out + 1 + (size_t)b * (EMB_C * HWB) + (size_t)cH * 128 * HWB + hw0;
  for (int p = 0; p < 2; ++p) {              // 2 passes of 64 c
    if (p) __syncthreads();                  // pass-0 stores done before rewrite
#pragma unroll
    for (int q = 0; q < 4; ++q) {            // 4 lanes x 16B = 64B/line per (nn,q)
      f32x4 v = *(const f32x4*)(er + p * 64 + q * 16 + ch * 4);
#pragma unroll
      for (int m = 0; m < 4; ++m)
        tile[(q * 16 + ch * 4 + m) * 65 + nn] = v[m];
    }
    __syncthreads();
#pragma unroll
    for (int cc = 0; cc < 16; ++cc) {        // wave w: c-rows w*16..w*16+15
      int cl = w * 16 + cc;
      ob[(size_t)(p * 64 + cl) * HWB + lane] = tile[cl * 65 + lane];  // 256B/wave
    }
  }
}

extern "C" void kernel_launch(void* const* d_in, const int* in_sizes, int n_in,
                              void* d_out, int out_size, void* d_ws, size_t ws_size,
                              hipStream_t stream) {
  const float* x   = (const float*)d_in[0];   // [16,256,64,64]
  const float* emb = (const float*)d_in[1];   // [1024,256]
  float* out = (float*)d_out;                 // [1 + 16777216]
  char*  ws  = (char*)d_ws;

  unsigned short* emb_bf = (unsigned short*)ws;                 // 512 KB
  float*          enorm  = (float*)(ws + 524288);               // 4 KB
  float*          loss   = (float*)(ws + 528384);               // 4 B
  float*          xn_g   = (float*)(ws + 532480);               // 256 KB
  unsigned*       keys_g = (unsigned*)(ws + 794624);            // 256 KB

  // A (bf16, fragment-ordered, 32 MB) lives inside the out payload at a 16B
  // offset. k_main reads it before k_out overwrites out[1..] (stream order).
  unsigned short* A = (unsigned short*)(out + 4);

  hipFuncSetAttribute((const void*)k_main,
                      hipFuncAttributeMaxDynamicSharedMemorySize, LDS_BYTES);

  k_emb <<<dim3(EMB_K),      dim3(EMB_C), 0,         stream>>>(emb, emb_bf, enorm, loss);
  k_tr  <<<dim3(NPIX / 64),  dim3(512),   0,         stream>>>(x, A, xn_g);
  k_main<<<dim3(NPIX / 256), dim3(512),   LDS_BYTES, stream>>>(A, emb_bf, enorm, xn_g,
                                                               keys_g, loss);
  k_out <<<dim3(NPIX / 32),  dim3(256),   0,         stream>>>(emb, keys_g, loss, out);
}

// Round 15
// 172.419 us; speedup vs baseline: 1.0148x; 1.0148x over previous
//
#include <hip/hip_runtime.h>
#include <hip/hip_bf16.h>
#include <cstdint>
#include <cstddef>

#define EMB_K   1024
#define EMB_C   256
#define HWB     4096        // 64*64 per batch
#define NPIX    65536       // 16*4096

typedef __bf16 bf16x8 __attribute__((ext_vector_type(8)));
typedef float  f32x4  __attribute__((ext_vector_type(4)));

__device__ __forceinline__ unsigned short bf16bits(float v) {
  __hip_bfloat16 h = __float2bfloat16(v);
  return __builtin_bit_cast(unsigned short, h);
}

// ---- emb -> bf16 row-major + fp32 norms; zero loss ----
__global__ void k_emb(const float* __restrict__ emb, unsigned short* __restrict__ emb_bf,
                      float* __restrict__ enorm, float* __restrict__ loss) {
  int k = blockIdx.x;      // 0..1023
  int c = threadIdx.x;     // 0..255
  if (k == 0 && c == 0) *loss = 0.f;
  float v = emb[(size_t)k * EMB_C + c];
  emb_bf[(size_t)k * EMB_C + c] = bf16bits(v);
  float s = v * v;
  for (int m = 32; m; m >>= 1) s += __shfl_down(s, m, 64);
  __shared__ float red[4];
  int lane = c & 63, w = c >> 6;
  if (lane == 0) red[w] = s;
  __syncthreads();
  if (c == 0) enorm[k] = red[0] + red[1] + red[2] + red[3];
}

// ================= transpose kernel: x -> A (FRAGMENT-ORDERED bf16) =================
// 1024 blocks x 512 thr, 32.25KB LDS -> 4 blocks/CU. Block owns 64 n.
// LDS-staged fragment tile, then LINEAR 1KB/wave dumps (R13's direct scatter
// was 64 txns/instr). Swizzle fix vs R14: XOR by the i-bits (local>>9), which
// VARY within a 16-lane quarter-wave — bank-group = (lr&7)^(i<<1) takes 8
// distinct values -> 2-way (free). R14's quad-XOR was quarter-constant ->
// still 8-way. Dump side: i constant per quarter -> conflict-free; XOR is an
// involution on bits 1-2 only.
__global__ __launch_bounds__(512) void
k_tr(const float* __restrict__ x, unsigned short* __restrict__ A,
     float* __restrict__ xn_g) {
  __shared__ uint4 tile[2048];               // 32KB, fragment-order chunks
  __shared__ float xn_l[64];
  int t  = threadIdx.x;
  int n0 = blockIdx.x * 64;
  int b  = n0 >> 12, hw0 = n0 & 4095;
  int hwq = t & 15, c8 = t >> 4;             // hwq: 4-n quad; c8 0..31 (8 c)
  if (t < 64) xn_l[t] = 0.f;
  __syncthreads();
  const float* xp = x + (size_t)b * (EMB_C * HWB) + hw0 + hwq * 4;
  float xn[4] = {0.f, 0.f, 0.f, 0.f};
  unsigned pk[4][4] = {};
#pragma unroll
  for (int j = 0; j < 8; ++j) {              // c = c8*8 + j
    f32x4 v = *(const f32x4*)(xp + (size_t)(c8 * 8 + j) * HWB);  // 16B/lane
#pragma unroll
    for (int m = 0; m < 4; ++m) {
      xn[m] += v[m] * v[m];
      pk[m][j >> 1] |= (unsigned)bf16bits(v[m]) << ((j & 1) * 16);
    }
  }
  int s = c8 >> 2, quad = c8 & 3;
#pragma unroll
  for (int m = 0; m < 4; ++m) {
    int nl = hwq * 4 + m;                    // n-local 0..63
    int i = nl >> 4, lr = nl & 15;
    int local = (i * 8 + s) * 64 + quad * 16 + lr;     // fragment-order chunk
    tile[local ^ (((local >> 9) & 3) << 1)] = *(const uint4*)pk[m];
    atomicAdd(&xn_l[nl], xn[m]);
  }
  __syncthreads();
  if (t < 64) xn_g[n0 + t] = xn_l[t];
  // dump: involution XOR on bits 1-2 (i bits 9-10 untouched); wave covers 64
  // consecutive d -> i constant per quarter -> conflict-free, 1KB coalesced.
  int blk = n0 >> 8, g = (n0 >> 6) & 3;
  uint4* dst = (uint4*)A + (size_t)blk * 8192 + g * 2048;
#pragma unroll
  for (int q = 0; q < 4; ++q) {
    int d = q * 512 + t;
    dst[d] = tile[d ^ (((d >> 9) & 3) << 1)];
  }
}

// ---- staging: 32 rows x 256c bf16 = 16KB, XOR-swizzled 16B chunks, glds ----
// 512-thread: 1024 chunks, 2 per thread (2 vmcnt units per stage)
__device__ __forceinline__ void stage32(const unsigned short* __restrict__ rows,
                                        unsigned char* buf, int t) {
#pragma unroll
  for (int j = 0; j < 2; ++j) {
    int d = j * 512 + t;             // linear dest chunk 0..1023
    int r = d >> 5;                  // row 0..31
    int slot = d & 31;
    int c16 = ((slot >> 3) << 3) | ((slot & 7) ^ (r & 7));
    const unsigned short* src = rows + (size_t)r * EMB_C + c16 * 8;
    __builtin_amdgcn_global_load_lds(
        (const __attribute__((address_space(1))) void*)src,
        (__attribute__((address_space(3))) void*)(buf + (unsigned)(j * 8192 + (t >> 6) * 1024)),
        16, 0, 0);
  }
}

// ================= main kernel: GEMM + argmin + loss =================
// THE GRID FIX: R13/R14 launched 256 blocks on 256 CUs -> 1 block/CU always;
// "2 blocks/CU" LDS sizing was vacuous. Now 512 blocks x 128 n, af[2][8] (32
// VGPR, ~90 total), 4x16KB bufs -> 70.7KB LDS -> REAL 2 blocks/CU: one
// block's MFMA hides the other's barrier/stage stalls. Counted-vmcnt depth-3
// rotation unchanged (peel 4/2/0, 2-chunk stages).
// LDS: [0,64K) bufs 4x16KB | cjl 4K | keys 512B | xn 512B | red
#define LDS_BYTES 70688

__global__ __launch_bounds__(512) void
k_main(const unsigned short* __restrict__ A, const unsigned short* __restrict__ embbf,
       const float* __restrict__ enorm, const float* __restrict__ xn_g,
       unsigned* __restrict__ keys_g, float* __restrict__ loss) {
  extern __shared__ char smem[];
  float*    cjl    = (float*)(smem + 65536);           // 1024 f32
  unsigned* keys_l = (unsigned*)(smem + 69632);        // 128 u32
  float*    xn_l   = (float*)(smem + 70144);           // 128 f32
  float*    red    = (float*)(smem + 70656);           // 8 f32

  int bm = blockIdx.x;
  int n0 = bm * 128;
  int t = threadIdx.x, w = t >> 6, lane = t & 63;
  int quad = lane >> 4, lr = lane & 15;
  int g  = w >> 1;       // n-group 0..3 (32 n)
  int h2 = w & 1;        // k-half (16 k of each 32k tile)

  // B(0)/B(1) staged early: latency hides under af load + init
  stage32(embbf,               (unsigned char*)smem,         t);
  stage32(embbf + 32 * EMB_C,  (unsigned char*)smem + 16384, t);

  if (t < 128) { keys_l[t] = 0u; xn_l[t] = xn_g[n0 + t]; }
  for (int i = t; i < 1024; i += 512) cjl[i] = 0.375f - 0.5f * enorm[i];

  // ---- af: direct coalesced loads from fragment-ordered A ----
  // n = (bm>>1)*256 + (bm&1)*128 + g*32 + i*16 + lr  ->  fragment row
  // fr = (bm&1)*8 + g*2 + i; chunk = (bm>>1)*8192 + (fr*8+s)*64 + lane.
  bf16x8 af[2][8];
  const uint4* Ab = (const uint4*)A + (size_t)(bm >> 1) * 8192 + (bm & 1) * 4096;
#pragma unroll
  for (int i = 0; i < 2; ++i)
#pragma unroll
    for (int s = 0; s < 8; ++s) {
      uint4 q = Ab[((g * 2 + i) * 8 + s) * 64 + lane];   // 1KB/wave coalesced
      af[i][s] = __builtin_bit_cast(bf16x8, q);
    }
  __syncthreads();   // LDS init visible; B(0)/B(1) glds drained

  // ---- K-loop: 32 tiles of 32 k; 4-buf rotation, 1 barrier + counted vmcnt ----
  unsigned best[2][4] = {};
  for (int kt = 0; kt < 32; ++kt) {
    if (kt < 30)
      stage32(embbf + (size_t)(kt + 2) * 32 * EMB_C,
              (unsigned char*)smem + (((kt + 2) & 3) << 14), t);
    // outstanding stages: kt,kt+1,kt+2 = 6 chunks -> wait oldest stage (2 each)
    if (kt < 30)       asm volatile("s_waitcnt vmcnt(4)" ::: "memory");
    else if (kt == 30) asm volatile("s_waitcnt vmcnt(2)" ::: "memory");
    else               asm volatile("s_waitcnt vmcnt(0)" ::: "memory");
    __builtin_amdgcn_s_barrier();              // all waves' stage(kt) landed
    __builtin_amdgcn_sched_barrier(0);         // no LDS-read hoist above
    const unsigned char* srcB = (const unsigned char*)smem + ((kt & 3) << 14);
    int k = kt * 32 + h2 * 16 + lr;
    float cj = cjl[k];
    unsigned kp = 1023u - (unsigned)k;
    f32x4 acc[2] = {};
#pragma unroll
    for (int s = 0; s < 8; ++s) {
      int cc = s * 4 + quad;
      int pos = ((cc >> 3) << 3) | ((cc & 7) ^ (lr & 7));   // rB&7 == lr&7
      bf16x8 bf = *(const bf16x8*)(srcB + (h2 * 16 + lr) * 512 + pos * 16);
#pragma unroll
      for (int i = 0; i < 2; ++i)
        acc[i] = __builtin_amdgcn_mfma_f32_16x16x32_bf16(af[i][s], bf, acc[i], 0, 0, 0);
    }
    // fold argmin keys: f = dot + 0.375 - 0.5||e||^2 in (0.04,0.71) -> positive
    // float u32-order-correct; low 10 mantissa bits carry (1023-k).
#pragma unroll
    for (int i = 0; i < 2; ++i)
#pragma unroll
      for (int r = 0; r < 4; ++r) {
        float f = acc[i][r] + cj;
        unsigned key = (__float_as_uint(f) & 0xFFFFFC00u) | kp;
        best[i][r] = best[i][r] > key ? best[i][r] : key;
      }
  }
  __syncthreads();   // k-loop complete before keys_l atomics phase

  // ---- combine keys across k-lanes; k-halves via LDS atomicMax ----
#pragma unroll
  for (int i = 0; i < 2; ++i)
#pragma unroll
    for (int r = 0; r < 4; ++r) {
      unsigned v = best[i][r];
#pragma unroll
      for (int m = 1; m < 16; m <<= 1) {
        unsigned o = (unsigned)__shfl_xor((int)v, m, 64);
        v = v > o ? v : o;
      }
      if (lr == 0) atomicMax(&keys_l[g * 32 + i * 16 + quad * 4 + r], v);
    }
  __syncthreads();

  // ---- keys export + loss partial: d2 = ||x||^2 + 0.75 - 2*f_hat ----
  if (t < 128) {
    unsigned key = keys_l[t];
    keys_g[n0 + t] = key;
    float fh = __uint_as_float(key & 0xFFFFFC00u);
    float lsum = xn_l[t] + 0.75f - 2.0f * fh;
    for (int m = 32; m; m >>= 1) lsum += __shfl_down(lsum, m, 64);
    if (lane == 0) red[w] = lsum;
  }
  __syncthreads();
  if (t == 0)
    atomicAdd(loss, red[0] + red[1]);   // device-scope
}

// ================= output kernel: gather + transpose + store =================
// 2048 blocks x 256 thr, 16.6KB LDS -> 8 blocks/CU = 32 waves/CU (proven R12:
// ~5.3 TB/s). Stride-65 LDS tile conflict-free both directions; 256B/wave
// scalar-row stores alignment-proof vs out+1. Loss finalize here.
__global__ __launch_bounds__(256) void
k_out(const float* __restrict__ emb, const unsigned* __restrict__ keys_g,
      const float* __restrict__ loss, float* __restrict__ out) {
  __shared__ float tile[64 * 65];            // 16.25 KB
  __shared__ int   idx_l[64];
  int e  = blockIdx.x;
  int nt = e >> 1, cH = e & 1;
  int n0 = nt * 64;
  int b  = n0 >> 12, hw0 = n0 & 4095;
  int t = threadIdx.x, w = t >> 6, lane = t & 63;
  if (e == 0 && t == 0)
    out[0] = 1.0625f * (*loss) / 16777216.0f;
  if (t < 64) idx_l[t] = 1023 - (int)(keys_g[n0 + t] & 1023u);
  __syncthreads();
  int nn = t >> 2, ch = t & 3;               // 4 threads per n
  const float* er = emb + (size_t)idx_l[nn] * EMB_C + cH * 128;
  float* ob = out + 1 + (size_t)b * (EMB_C * HWB) + (size_t)cH * 128 * HWB + hw0;
  for (int p = 0; p < 2; ++p) {              // 2 passes of 64 c
    if (p) __syncthreads();                  // pass-0 stores done before rewrite
#pragma unroll
    for (int q = 0; q < 4; ++q) {            // 4 lanes x 16B = 64B/line per (nn,q)
      f32x4 v = *(const f32x4*)(er + p * 64 + q * 16 + ch * 4);
#pragma unroll
      for (int m = 0; m < 4; ++m)
        tile[(q * 16 + ch * 4 + m) * 65 + nn] = v[m];
    }
    __syncthreads();
#pragma unroll
    for (int cc = 0; cc < 16; ++cc) {        // wave w: c-rows w*16..w*16+15
      int cl = w * 16 + cc;
      ob[(size_t)(p * 64 + cl) * HWB + lane] = tile[cl * 65 + lane];  // 256B/wave
    }
  }
}

extern "C" void kernel_launch(void* const* d_in, const int* in_sizes, int n_in,
                              void* d_out, int out_size, void* d_ws, size_t ws_size,
                              hipStream_t stream) {
  const float* x   = (const float*)d_in[0];   // [16,256,64,64]
  const float* emb = (const float*)d_in[1];   // [1024,256]
  float* out = (float*)d_out;                 // [1 + 16777216]
  char*  ws  = (char*)d_ws;

  unsigned short* emb_bf = (unsigned short*)ws;                 // 512 KB
  float*          enorm  = (float*)(ws + 524288);               // 4 KB
  float*          loss   = (float*)(ws + 528384);               // 4 B
  float*          xn_g   = (float*)(ws + 532480);               // 256 KB
  unsigned*       keys_g = (unsigned*)(ws + 794624);            // 256 KB

  // A (bf16, fragment-ordered, 32 MB) lives inside the out payload at a 16B
  // offset. k_main reads it before k_out overwrites out[1..] (stream order).
  unsigned short* A = (unsigned short*)(out + 4);

  hipFuncSetAttribute((const void*)k_main,
                      hipFuncAttributeMaxDynamicSharedMemorySize, LDS_BYTES);

  k_emb <<<dim3(EMB_K),      dim3(EMB_C), 0,         stream>>>(emb, emb_bf, enorm, loss);
  k_tr  <<<dim3(NPIX / 64),  dim3(512),   0,         stream>>>(x, A, xn_g);
  k_main<<<dim3(NPIX / 128), dim3(512),   LDS_BYTES, stream>>>(A, emb_bf, enorm, xn_g,
                                                               keys_g, loss);
  k_out <<<dim3(NPIX / 32),  dim3(256),   0,         stream>>>(emb, keys_g, loss, out);
}

// Round 16
// 152.924 us; speedup vs baseline: 1.1442x; 1.1275x over previous
//
#include <hip/hip_runtime.h>
#include <hip/hip_bf16.h>
#include <cstdint>
#include <cstddef>

#define EMB_K   1024
#define EMB_C   256
#define HWB     4096        // 64*64 per batch
#define NPIX    65536       // 16*4096

typedef __bf16 bf16x8 __attribute__((ext_vector_type(8)));
typedef float  f32x4  __attribute__((ext_vector_type(4)));

__device__ __forceinline__ unsigned short bf16bits(float v) {
  __hip_bfloat16 h = __float2bfloat16(v);
  return __builtin_bit_cast(unsigned short, h);
}

// ---- emb -> bf16 FRAGMENT-ORDERED + fp32 norms; zero loss ----
// Layout (16B chunks): tile kt (64 rows) contiguous 32KB. Element (k,c):
//   kt=k>>6, g2=(k>>4)&3, lr=k&15; s=c>>5, quad=(c>>3)&3, j=c&7
//   -> chunk = kt*2048 + (g2*8+s)*64 + quad*16 + lr, short = chunk*8+j.
// k_main's B path becomes: linear glds staging + lane-consecutive
// ds_read_b128 (conflict-free, no swizzle VALU). Values byte-identical to the
// old row-major read (rB=h2*32+j*16+lr, cols (s*4+quad)*8..).
__global__ void k_emb(const float* __restrict__ emb, unsigned short* __restrict__ emb_bf,
                      float* __restrict__ enorm, float* __restrict__ loss) {
  int k = blockIdx.x;      // 0..1023
  int c = threadIdx.x;     // 0..255
  if (k == 0 && c == 0) *loss = 0.f;
  float v = emb[(size_t)k * EMB_C + c];
  int kt = k >> 6, g2 = (k >> 4) & 3, lr = k & 15;
  int s = c >> 5, quad = (c >> 3) & 3, j = c & 7;
  size_t chunk = (size_t)kt * 2048 + (size_t)((g2 * 8 + s) * 64 + quad * 16 + lr);
  emb_bf[chunk * 8 + j] = bf16bits(v);
  float sq = v * v;
  for (int m = 32; m; m >>= 1) sq += __shfl_down(sq, m, 64);
  __shared__ float red[4];
  int lane = c & 63, w = c >> 6;
  if (lane == 0) red[w] = sq;
  __syncthreads();
  if (c == 0) enorm[k] = red[0] + red[1] + red[2] + red[3];
}

// ---- staging: one fragment-ordered 64-row tile (32KB), pure linear DMA ----
__device__ __forceinline__ void stage64(const unsigned short* __restrict__ tile_src,
                                        unsigned char* buf, int t) {
#pragma unroll
  for (int j = 0; j < 4; ++j) {
    int d = j * 512 + t;             // chunk 0..2047
    __builtin_amdgcn_global_load_lds(
        (const __attribute__((address_space(1))) void*)(tile_src + (size_t)d * 8),
        (__attribute__((address_space(3))) void*)(buf + (unsigned)(j * 8192 + (t >> 6) * 1024)),
        16, 0, 0);
  }
}

// A-tile swizzle (prologue LDS tile only) — proven R12.
__device__ __forceinline__ int posA(int cc, int nl) {
  return ((cc >> 3) << 3) | ((cc & 7) ^ ((nl ^ (nl >> 2)) & 7));
}

// ================= main kernel: transpose + GEMM + argmin + loss =================
// R12 champion structure + (1) fragment-ordered B (conflict-free k-loop reads,
// linear staging), (2) xn via shfl+partials (no 16-way LDS atomics).
// 256 blocks x 512 thr, af[4][8], counted-vmcnt 4-buf rotation.
// LDS: [0,128K) bufs 4x32KB (A-tile in bufs 2/3 during prologue) |
//      cjl 4K | keys 1K | xn 1K | xn_p 4K | red
#define LDS_BYTES 141376

__global__ __launch_bounds__(512) void
k_main(const float* __restrict__ x, const unsigned short* __restrict__ embbf,
       const float* __restrict__ enorm, unsigned* __restrict__ keys_g,
       float* __restrict__ loss) {
  extern __shared__ char smem[];
  unsigned char* Abase = (unsigned char*)smem + 65536;  // A-tile in bufs 2/3
  float*    cjl    = (float*)(smem + 131072);          // 1024 f32
  unsigned* keys_l = (unsigned*)(smem + 135168);       // 256 u32
  float*    xn_l   = (float*)(smem + 136192);          // 256 f32
  float*    xn_p   = (float*)(smem + 137216);          // 8 x 128 f32
  float*    red    = (float*)(smem + 141312);          // 16 f32

  int n0 = blockIdx.x * 256;
  int b  = n0 >> 12, hw0 = n0 & 4095;
  int t = threadIdx.x, w = t >> 6, lane = t & 63;
  int quad = lane >> 4, lr = lane & 15;
  int g  = w >> 1;       // n-group 0..3 (64 n)
  int h2 = w & 1;        // k-half (32 k of each 64k tile)

  // B(0)/B(1) staged early: latency hides under the whole prologue
  stage64(embbf,          (unsigned char*)smem,         t);
  stage64(embbf + 16384,  (unsigned char*)smem + 32768, t);

  if (t < 256) keys_l[t] = 0u;
  for (int i = t; i < 1024; i += 512) cjl[i] = 0.375f - 0.5f * enorm[i];
  __syncthreads();

  // ---- prologue: x[c][hw] -> A-tile bf16 (2 passes of 128 n); float4 reads ----
  bf16x8 af[4][8];
#pragma unroll
  for (int p = 0; p < 2; ++p) {
    if (p) __syncthreads();            // pass-0 af/xn_p reads done before rewrite
    int hwq = t & 31;                  // 4-hw quad -> n-local = hwq*4..+3
    int cg  = t >> 5;                  // c-group 0..15 (16 c each)
    float xn[4] = {0.f, 0.f, 0.f, 0.f};
    {
      const float* xp = x + (size_t)b * (EMB_C * HWB) + hw0 + p * 128 + hwq * 4;
      unsigned pk[4][8] = {};
#pragma unroll
      for (int j = 0; j < 16; ++j) {   // c = cg*16 + j
        f32x4 v = *(const f32x4*)(xp + (size_t)(cg * 16 + j) * HWB);  // 16B/lane
#pragma unroll
        for (int m = 0; m < 4; ++m) {
          xn[m] += v[m] * v[m];
          pk[m][j >> 1] |= (unsigned)bf16bits(v[m]) << ((j & 1) * 16);
        }
      }
#pragma unroll
      for (int m = 0; m < 4; ++m) {
        int nl = hwq * 4 + m;
        *(uint4*)(Abase + nl * 512 + posA(cg * 2,     nl) * 16) = *(const uint4*)&pk[m][0];
        *(uint4*)(Abase + nl * 512 + posA(cg * 2 + 1, nl) * 16) = *(const uint4*)&pk[m][4];
      }
    }
    // xn: lanes L and L+32 share nl (cg pair) -> shfl; per-wave partial row
#pragma unroll
    for (int m = 0; m < 4; ++m) xn[m] += __shfl_xor(xn[m], 32, 64);
    if (lane < 32) {
#pragma unroll
      for (int m = 0; m < 4; ++m) xn_p[w * 128 + lane * 4 + m] = xn[m];
    }
    __syncthreads();
    if (t < 128) {                     // reduce 8 wave-partials -> xn_l
      float sum = 0.f;
#pragma unroll
      for (int ww = 0; ww < 8; ++ww) sum += xn_p[ww * 128 + t];
      xn_l[p * 128 + t] = sum;
    }
    if ((g >> 1) == p) {               // n-groups {2p, 2p+1} load af this pass
#pragma unroll
      for (int i = 0; i < 4; ++i) {
        int rA = (g & 1) * 64 + i * 16 + lr;   // local row in this pass's 128
#pragma unroll
        for (int s = 0; s < 8; ++s) {
          int cc = s * 4 + quad;
          af[i][s] = *(const bf16x8*)(Abase + rA * 512 + posA(cc, rA) * 16);
        }
      }
    }
  }
  __syncthreads();   // af complete (drains vmcnt -> bufs 0/1 landed)

  // ---- K-loop: 16 tiles of 64 k; 4-buf rotation, 1 barrier + counted vmcnt ----
  unsigned best[4][4] = {};
  for (int kt = 0; kt < 16; ++kt) {
    if (kt < 14)
      stage64(embbf + (size_t)(kt + 2) * 16384,
              (unsigned char*)smem + (((kt + 2) & 3) << 15), t);
    // outstanding stages: kt,kt+1,kt+2 = 12 chunks -> wait oldest stage (4 each)
    if (kt < 14)       asm volatile("s_waitcnt vmcnt(8)" ::: "memory");
    else if (kt == 14) asm volatile("s_waitcnt vmcnt(4)" ::: "memory");
    else               asm volatile("s_waitcnt vmcnt(0)" ::: "memory");
    __builtin_amdgcn_s_barrier();              // all waves' stage(kt) landed
    __builtin_amdgcn_sched_barrier(0);         // no LDS-read hoist above
    const uint4* sb = (const uint4*)(smem + ((kt & 3) << 15));
    float cj[2]; unsigned kp[2];
#pragma unroll
    for (int j = 0; j < 2; ++j) {
      int k = kt * 64 + h2 * 32 + j * 16 + lr;
      cj[j] = cjl[k];
      kp[j] = 1023u - (unsigned)k;
    }
    f32x4 acc[4][2] = {};
#pragma unroll
    for (int s = 0; s < 8; ++s) {
      bf16x8 bf[2];
#pragma unroll
      for (int j = 0; j < 2; ++j) {
        uint4 q = sb[((h2 * 2 + j) * 8 + s) * 64 + lane];   // conflict-free b128
        bf[j] = __builtin_bit_cast(bf16x8, q);
      }
#pragma unroll
      for (int i = 0; i < 4; ++i)
#pragma unroll
        for (int j = 0; j < 2; ++j)
          acc[i][j] = __builtin_amdgcn_mfma_f32_16x16x32_bf16(af[i][s], bf[j], acc[i][j], 0, 0, 0);
    }
    // fold argmin keys: f = dot + 0.375 - 0.5||e||^2 in (0.04,0.71) -> positive
    // float u32-order-correct; low 10 mantissa bits carry (1023-k).
#pragma unroll
    for (int i = 0; i < 4; ++i)
#pragma unroll
      for (int j = 0; j < 2; ++j)
#pragma unroll
        for (int r = 0; r < 4; ++r) {
          float f = acc[i][j][r] + cj[j];
          unsigned key = (__float_as_uint(f) & 0xFFFFFC00u) | kp[j];
          best[i][r] = best[i][r] > key ? best[i][r] : key;
        }
  }
  __syncthreads();   // k-loop complete before keys_l atomics phase

  // ---- combine keys across k-lanes; k-halves via LDS atomicMax ----
#pragma unroll
  for (int i = 0; i < 4; ++i)
#pragma unroll
    for (int r = 0; r < 4; ++r) {
      unsigned v = best[i][r];
#pragma unroll
      for (int m = 1; m < 16; m <<= 1) {
        unsigned o = (unsigned)__shfl_xor((int)v, m, 64);
        v = v > o ? v : o;
      }
      if (lr == 0) atomicMax(&keys_l[g * 64 + i * 16 + quad * 4 + r], v);
    }
  __syncthreads();

  // ---- keys export + loss partial: d2 = ||x||^2 + 0.75 - 2*f_hat ----
  if (t < 256) {
    unsigned key = keys_l[t];
    keys_g[n0 + t] = key;
    float fh = __uint_as_float(key & 0xFFFFFC00u);
    float lsum = xn_l[t] + 0.75f - 2.0f * fh;
    for (int m = 32; m; m >>= 1) lsum += __shfl_down(lsum, m, 64);
    if (lane == 0) red[w] = lsum;
  }
  __syncthreads();
  if (t == 0)
    atomicAdd(loss, red[0] + red[1] + red[2] + red[3]);   // device-scope
}

// ================= output kernel: gather + transpose + store =================
// 2048 blocks x 256 thr, 16.6KB LDS -> 8 blocks/CU = 32 waves/CU (proven R12:
// ~5.3 TB/s). Stride-65 LDS tile conflict-free both directions; 256B/wave
// scalar-row stores alignment-proof vs out+1. Loss finalize here.
__global__ __launch_bounds__(256) void
k_out(const float* __restrict__ emb, const unsigned* __restrict__ keys_g,
      const float* __restrict__ loss, float* __restrict__ out) {
  __shared__ float tile[64 * 65];            // 16.25 KB
  __shared__ int   idx_l[64];
  int e  = blockIdx.x;
  int nt = e >> 1, cH = e & 1;
  int n0 = nt * 64;
  int b  = n0 >> 12, hw0 = n0 & 4095;
  int t = threadIdx.x, w = t >> 6, lane = t & 63;
  if (e == 0 && t == 0)
    out[0] = 1.0625f * (*loss) / 16777216.0f;
  if (t < 64) idx_l[t] = 1023 - (int)(keys_g[n0 + t] & 1023u);
  __syncthreads();
  int nn = t >> 2, ch = t & 3;               // 4 threads per n
  const float* er = emb + (size_t)idx_l[nn] * EMB_C + cH * 128;
  float* ob = out + 1 + (size_t)b * (EMB_C * HWB) + (size_t)cH * 128 * HWB + hw0;
  for (int p = 0; p < 2; ++p) {              // 2 passes of 64 c
    if (p) __syncthreads();                  // pass-0 stores done before rewrite
#pragma unroll
    for (int q = 0; q < 4; ++q) {            // 4 lanes x 16B = 64B/line per (nn,q)
      f32x4 v = *(const f32x4*)(er + p * 64 + q * 16 + ch * 4);
#pragma unroll
      for (int m = 0; m < 4; ++m)
        tile[(q * 16 + ch * 4 + m) * 65 + nn] = v[m];
    }
    __syncthreads();
#pragma unroll
    for (int cc = 0; cc < 16; ++cc) {        // wave w: c-rows w*16..w*16+15
      int cl = w * 16 + cc;
      ob[(size_t)(p * 64 + cl) * HWB + lane] = tile[cl * 65 + lane];  // 256B/wave
    }
  }
}

extern "C" void kernel_launch(void* const* d_in, const int* in_sizes, int n_in,
                              void* d_out, int out_size, void* d_ws, size_t ws_size,
                              hipStream_t stream) {
  const float* x   = (const float*)d_in[0];   // [16,256,64,64]
  const float* emb = (const float*)d_in[1];   // [1024,256]
  float* out = (float*)d_out;                 // [1 + 16777216]
  char*  ws  = (char*)d_ws;

  unsigned short* emb_bf = (unsigned short*)ws;                 // 512 KB (fragment-ordered)
  float*          enorm  = (float*)(ws + 524288);               // 4 KB
  float*          loss   = (float*)(ws + 528384);               // 4 B
  unsigned*       keys_g = (unsigned*)(ws + 532480);            // 256 KB

  hipFuncSetAttribute((const void*)k_main,
                      hipFuncAttributeMaxDynamicSharedMemorySize, LDS_BYTES);

  k_emb <<<dim3(EMB_K),      dim3(EMB_C), 0,         stream>>>(emb, emb_bf, enorm, loss);
  k_main<<<dim3(NPIX / 256), dim3(512),   LDS_BYTES, stream>>>(x, emb_bf, enorm,
                                                               keys_g, loss);
  k_out <<<dim3(NPIX / 32),  dim3(256),   0,         stream>>>(emb, keys_g, loss, out);
}

// Round 17
// 151.688 us; speedup vs baseline: 1.1535x; 1.0081x over previous
//
#include <hip/hip_runtime.h>
#include <hip/hip_bf16.h>
#include <cstdint>
#include <cstddef>

#define EMB_K   1024
#define EMB_C   256
#define HWB     4096        // 64*64 per batch
#define NPIX    65536       // 16*4096

typedef __bf16 bf16x8 __attribute__((ext_vector_type(8)));
typedef float  f32x4  __attribute__((ext_vector_type(4)));

__device__ __forceinline__ unsigned short bf16bits(float v) {
  __hip_bfloat16 h = __float2bfloat16(v);
  return __builtin_bit_cast(unsigned short, h);
}

// ---- emb -> bf16 FRAGMENT-ORDERED + fp32 norms; zero loss ----
// Layout (16B chunks): tile kt (64 rows) contiguous 32KB. Element (k,c):
//   kt=k>>6, g2=(k>>4)&3, lr=k&15; s=c>>5, quad=(c>>3)&3, j=c&7
//   -> chunk = kt*2048 + (g2*8+s)*64 + quad*16 + lr, short = chunk*8+j.
// k_main's B path: linear glds staging + lane-consecutive ds_read_b128
// (conflict-free — proven R16: SQ_LDS_BANK_CONFLICT 2.36M -> 311K).
__global__ void k_emb(const float* __restrict__ emb, unsigned short* __restrict__ emb_bf,
                      float* __restrict__ enorm, float* __restrict__ loss) {
  int k = blockIdx.x;      // 0..1023
  int c = threadIdx.x;     // 0..255
  if (k == 0 && c == 0) *loss = 0.f;
  float v = emb[(size_t)k * EMB_C + c];
  int kt = k >> 6, g2 = (k >> 4) & 3, lr = k & 15;
  int s = c >> 5, quad = (c >> 3) & 3, j = c & 7;
  size_t chunk = (size_t)kt * 2048 + (size_t)((g2 * 8 + s) * 64 + quad * 16 + lr);
  emb_bf[chunk * 8 + j] = bf16bits(v);
  float sq = v * v;
  for (int m = 32; m; m >>= 1) sq += __shfl_down(sq, m, 64);
  __shared__ float red[4];
  int lane = c & 63, w = c >> 6;
  if (lane == 0) red[w] = sq;
  __syncthreads();
  if (c == 0) enorm[k] = red[0] + red[1] + red[2] + red[3];
}

// ---- staging: one fragment-ordered 64-row tile (32KB), pure linear DMA ----
__device__ __forceinline__ void stage64(const unsigned short* __restrict__ tile_src,
                                        unsigned char* buf, int t) {
#pragma unroll
  for (int j = 0; j < 4; ++j) {
    int d = j * 512 + t;             // chunk 0..2047
    __builtin_amdgcn_global_load_lds(
        (const __attribute__((address_space(1))) void*)(tile_src + (size_t)d * 8),
        (__attribute__((address_space(3))) void*)(buf + (unsigned)(j * 8192 + (t >> 6) * 1024)),
        16, 0, 0);
  }
}

// A-tile swizzle (prologue LDS tile only) — proven R12.
__device__ __forceinline__ int posA(int cc, int nl) {
  return ((cc >> 3) << 3) | ((cc & 7) ^ ((nl ^ (nl >> 2)) & 7));
}

// ================= main kernel: transpose + GEMM + argmin + loss =================
// R16 CHAMPION — byte-identical this round (single-variable discipline).
// 256 blocks x 512 thr, af[4][8], counted-vmcnt 4-buf rotation,
// fragment-ordered conflict-free B, xn via shfl+partials.
// LDS: [0,128K) bufs 4x32KB (A-tile in bufs 2/3 during prologue) |
//      cjl 4K | keys 1K | xn 1K | xn_p 4K | red
#define LDS_BYTES 141376

__global__ __launch_bounds__(512) void
k_main(const float* __restrict__ x, const unsigned short* __restrict__ embbf,
       const float* __restrict__ enorm, unsigned* __restrict__ keys_g,
       float* __restrict__ loss) {
  extern __shared__ char smem[];
  unsigned char* Abase = (unsigned char*)smem + 65536;  // A-tile in bufs 2/3
  float*    cjl    = (float*)(smem + 131072);          // 1024 f32
  unsigned* keys_l = (unsigned*)(smem + 135168);       // 256 u32
  float*    xn_l   = (float*)(smem + 136192);          // 256 f32
  float*    xn_p   = (float*)(smem + 137216);          // 8 x 128 f32
  float*    red    = (float*)(smem + 141312);          // 16 f32

  int n0 = blockIdx.x * 256;
  int b  = n0 >> 12, hw0 = n0 & 4095;
  int t = threadIdx.x, w = t >> 6, lane = t & 63;
  int quad = lane >> 4, lr = lane & 15;
  int g  = w >> 1;       // n-group 0..3 (64 n)
  int h2 = w & 1;        // k-half (32 k of each 64k tile)

  // B(0)/B(1) staged early: latency hides under the whole prologue
  stage64(embbf,          (unsigned char*)smem,         t);
  stage64(embbf + 16384,  (unsigned char*)smem + 32768, t);

  if (t < 256) keys_l[t] = 0u;
  for (int i = t; i < 1024; i += 512) cjl[i] = 0.375f - 0.5f * enorm[i];
  __syncthreads();

  // ---- prologue: x[c][hw] -> A-tile bf16 (2 passes of 128 n); float4 reads ----
  bf16x8 af[4][8];
#pragma unroll
  for (int p = 0; p < 2; ++p) {
    if (p) __syncthreads();            // pass-0 af/xn_p reads done before rewrite
    int hwq = t & 31;                  // 4-hw quad -> n-local = hwq*4..+3
    int cg  = t >> 5;                  // c-group 0..15 (16 c each)
    float xn[4] = {0.f, 0.f, 0.f, 0.f};
    {
      const float* xp = x + (size_t)b * (EMB_C * HWB) + hw0 + p * 128 + hwq * 4;
      unsigned pk[4][8] = {};
#pragma unroll
      for (int j = 0; j < 16; ++j) {   // c = cg*16 + j
        f32x4 v = *(const f32x4*)(xp + (size_t)(cg * 16 + j) * HWB);  // 16B/lane
#pragma unroll
        for (int m = 0; m < 4; ++m) {
          xn[m] += v[m] * v[m];
          pk[m][j >> 1] |= (unsigned)bf16bits(v[m]) << ((j & 1) * 16);
        }
      }
#pragma unroll
      for (int m = 0; m < 4; ++m) {
        int nl = hwq * 4 + m;
        *(uint4*)(Abase + nl * 512 + posA(cg * 2,     nl) * 16) = *(const uint4*)&pk[m][0];
        *(uint4*)(Abase + nl * 512 + posA(cg * 2 + 1, nl) * 16) = *(const uint4*)&pk[m][4];
      }
    }
    // xn: lanes L and L+32 share nl (cg pair) -> shfl; per-wave partial row
#pragma unroll
    for (int m = 0; m < 4; ++m) xn[m] += __shfl_xor(xn[m], 32, 64);
    if (lane < 32) {
#pragma unroll
      for (int m = 0; m < 4; ++m) xn_p[w * 128 + lane * 4 + m] = xn[m];
    }
    __syncthreads();
    if (t < 128) {                     // reduce 8 wave-partials -> xn_l
      float sum = 0.f;
#pragma unroll
      for (int ww = 0; ww < 8; ++ww) sum += xn_p[ww * 128 + t];
      xn_l[p * 128 + t] = sum;
    }
    if ((g >> 1) == p) {               // n-groups {2p, 2p+1} load af this pass
#pragma unroll
      for (int i = 0; i < 4; ++i) {
        int rA = (g & 1) * 64 + i * 16 + lr;   // local row in this pass's 128
#pragma unroll
        for (int s = 0; s < 8; ++s) {
          int cc = s * 4 + quad;
          af[i][s] = *(const bf16x8*)(Abase + rA * 512 + posA(cc, rA) * 16);
        }
      }
    }
  }
  __syncthreads();   // af complete (drains vmcnt -> bufs 0/1 landed)

  // ---- K-loop: 16 tiles of 64 k; 4-buf rotation, 1 barrier + counted vmcnt ----
  unsigned best[4][4] = {};
  for (int kt = 0; kt < 16; ++kt) {
    if (kt < 14)
      stage64(embbf + (size_t)(kt + 2) * 16384,
              (unsigned char*)smem + (((kt + 2) & 3) << 15), t);
    // outstanding stages: kt,kt+1,kt+2 = 12 chunks -> wait oldest stage (4 each)
    if (kt < 14)       asm volatile("s_waitcnt vmcnt(8)" ::: "memory");
    else if (kt == 14) asm volatile("s_waitcnt vmcnt(4)" ::: "memory");
    else               asm volatile("s_waitcnt vmcnt(0)" ::: "memory");
    __builtin_amdgcn_s_barrier();              // all waves' stage(kt) landed
    __builtin_amdgcn_sched_barrier(0);         // no LDS-read hoist above
    const uint4* sb = (const uint4*)(smem + ((kt & 3) << 15));
    float cj[2]; unsigned kp[2];
#pragma unroll
    for (int j = 0; j < 2; ++j) {
      int k = kt * 64 + h2 * 32 + j * 16 + lr;
      cj[j] = cjl[k];
      kp[j] = 1023u - (unsigned)k;
    }
    f32x4 acc[4][2] = {};
#pragma unroll
    for (int s = 0; s < 8; ++s) {
      bf16x8 bf[2];
#pragma unroll
      for (int j = 0; j < 2; ++j) {
        uint4 q = sb[((h2 * 2 + j) * 8 + s) * 64 + lane];   // conflict-free b128
        bf[j] = __builtin_bit_cast(bf16x8, q);
      }
#pragma unroll
      for (int i = 0; i < 4; ++i)
#pragma unroll
        for (int j = 0; j < 2; ++j)
          acc[i][j] = __builtin_amdgcn_mfma_f32_16x16x32_bf16(af[i][s], bf[j], acc[i][j], 0, 0, 0);
    }
    // fold argmin keys: f = dot + 0.375 - 0.5||e||^2 in (0.04,0.71) -> positive
    // float u32-order-correct; low 10 mantissa bits carry (1023-k).
#pragma unroll
    for (int i = 0; i < 4; ++i)
#pragma unroll
      for (int j = 0; j < 2; ++j)
#pragma unroll
        for (int r = 0; r < 4; ++r) {
          float f = acc[i][j][r] + cj[j];
          unsigned key = (__float_as_uint(f) & 0xFFFFFC00u) | kp[j];
          best[i][r] = best[i][r] > key ? best[i][r] : key;
        }
  }
  __syncthreads();   // k-loop complete before keys_l atomics phase

  // ---- combine keys across k-lanes; k-halves via LDS atomicMax ----
#pragma unroll
  for (int i = 0; i < 4; ++i)
#pragma unroll
    for (int r = 0; r < 4; ++r) {
      unsigned v = best[i][r];
#pragma unroll
      for (int m = 1; m < 16; m <<= 1) {
        unsigned o = (unsigned)__shfl_xor((int)v, m, 64);
        v = v > o ? v : o;
      }
      if (lr == 0) atomicMax(&keys_l[g * 64 + i * 16 + quad * 4 + r], v);
    }
  __syncthreads();

  // ---- keys export + loss partial: d2 = ||x||^2 + 0.75 - 2*f_hat ----
  if (t < 256) {
    unsigned key = keys_l[t];
    keys_g[n0 + t] = key;
    float fh = __uint_as_float(key & 0xFFFFFC00u);
    float lsum = xn_l[t] + 0.75f - 2.0f * fh;
    for (int m = 32; m; m >>= 1) lsum += __shfl_down(lsum, m, 64);
    if (lane == 0) red[w] = lsum;
  }
  __syncthreads();
  if (t == 0)
    atomicAdd(loss, red[0] + red[1] + red[2] + red[3]);   // device-scope
}

// ================= output kernel: gather + transpose + store =================
// 2048 blocks x 256 thr, ~17.7KB LDS -> 8 blocks/CU = 32 waves/CU.
// R17 delta: 16B/lane VECTOR stores (was 4B scalar). out+1 misalignment
// absorbed by rotate-by-3 tile (R11-proven): tile[row*68 + (n-3)&63]; store
// lane i reads aligned ds_read_b128 at 4i and writes aligned f32x4 at F+3+4i;
// lane 15 of each 16-lane row group peels head (F[0..2]) + tail (F[63]).
// Stride 68 keeps b128 16B-aligned; write banks (16ch+u) 2-way = free.
__global__ __launch_bounds__(256) void
k_out(const float* __restrict__ emb, const unsigned* __restrict__ keys_g,
      const float* __restrict__ loss, float* __restrict__ out) {
  __shared__ float tile[64 * 68];            // 17 KB
  __shared__ int   idx_l[64];
  int e  = blockIdx.x;
  int nt = e >> 1, cH = e & 1;
  int n0 = nt * 64;
  int b  = n0 >> 12, hw0 = n0 & 4095;
  int t = threadIdx.x, w = t >> 6, lane = t & 63;
  if (e == 0 && t == 0)
    out[0] = 1.0625f * (*loss) / 16777216.0f;
  if (t < 64) idx_l[t] = 1023 - (int)(keys_g[n0 + t] & 1023u);
  __syncthreads();
  int nn = t >> 2, ch = t & 3;               // 4 threads per n
  int nrot = (nn - 3) & 63;                  // rotate-by-3 for aligned stores
  const float* er = emb + (size_t)idx_l[nn] * EMB_C + cH * 128;
  float* ob = out + 1 + (size_t)b * (EMB_C * HWB) + (size_t)cH * 128 * HWB + hw0;
  for (int p = 0; p < 2; ++p) {              // 2 passes of 64 c
    if (p) __syncthreads();                  // pass-0 stores done before rewrite
#pragma unroll
    for (int q = 0; q < 4; ++q) {            // 4 lanes x 16B = 64B/line per (nn,q)
      f32x4 v = *(const f32x4*)(er + p * 64 + q * 16 + ch * 4);
#pragma unroll
      for (int m = 0; m < 4; ++m)
        tile[(q * 16 + ch * 4 + m) * 68 + nrot] = v[m];
    }
    __syncthreads();
#pragma unroll
    for (int cc = 0; cc < 4; ++cc) {         // 4 rows per iter x 4 iters = 16/wave
      int cl = w * 16 + cc * 4 + (lane >> 4);
      int i  = lane & 15;                    // 16 lanes per row
      const float* tr = tile + cl * 68;
      float* F = ob + (size_t)(p * 64 + cl) * HWB;
      if (i < 15) {
        f32x4 qv = *(const f32x4*)(tr + 4 * i);      // aligned b128 (68 = 4*17)
        *(f32x4*)(F + 3 + 4 * i) = qv;               // aligned 16B store
      } else {
        F[0] = tr[61]; F[1] = tr[62]; F[2] = tr[63]; // head n=0,1,2
        F[63] = tr[60];                              // tail n=63
      }
    }
  }
}

extern "C" void kernel_launch(void* const* d_in, const int* in_sizes, int n_in,
                              void* d_out, int out_size, void* d_ws, size_t ws_size,
                              hipStream_t stream) {
  const float* x   = (const float*)d_in[0];   // [16,256,64,64]
  const float* emb = (const float*)d_in[1];   // [1024,256]
  float* out = (float*)d_out;                 // [1 + 16777216]
  char*  ws  = (char*)d_ws;

  unsigned short* emb_bf = (unsigned short*)ws;                 // 512 KB (fragment-ordered)
  float*          enorm  = (float*)(ws + 524288);               // 4 KB
  float*          loss   = (float*)(ws + 528384);               // 4 B
  unsigned*       keys_g = (unsigned*)(ws + 532480);            // 256 KB

  hipFuncSetAttribute((const void*)k_main,
                      hipFuncAttributeMaxDynamicSharedMemorySize, LDS_BYTES);

  k_emb <<<dim3(EMB_K),      dim3(EMB_C), 0,         stream>>>(emb, emb_bf, enorm, loss);
  k_main<<<dim3(NPIX / 256), dim3(512),   LDS_BYTES, stream>>>(x, emb_bf, enorm,
                                                               keys_g, loss);
  k_out <<<dim3(NPIX / 32),  dim3(256),   0,         stream>>>(emb, keys_g, loss, out);
}

// Round 18
// 150.327 us; speedup vs baseline: 1.1640x; 1.0091x over previous
//
#include <hip/hip_runtime.h>
#include <hip/hip_bf16.h>
#include <cstdint>
#include <cstddef>

#define EMB_K   1024
#define EMB_C   256
#define HWB     4096        // 64*64 per batch
#define NPIX    65536       // 16*4096

typedef __bf16 bf16x8 __attribute__((ext_vector_type(8)));
typedef float  f32x4  __attribute__((ext_vector_type(4)));

__device__ __forceinline__ unsigned short bf16bits(float v) {
  __hip_bfloat16 h = __float2bfloat16(v);
  return __builtin_bit_cast(unsigned short, h);
}

// ---- emb -> bf16 FRAGMENT-ORDERED + fp32 norms; zero loss ----
// Layout (16B chunks): tile kt (64 rows) contiguous 32KB. Element (k,c):
//   kt=k>>6, g2=(k>>4)&3, lr=k&15; s=c>>5, quad=(c>>3)&3, j=c&7
//   -> chunk = kt*2048 + (g2*8+s)*64 + quad*16 + lr, short = chunk*8+j.
// k_main's B path: linear glds staging + lane-consecutive ds_read_b128
// (conflict-free — proven R16: SQ_LDS_BANK_CONFLICT 2.36M -> 311K).
__global__ void k_emb(const float* __restrict__ emb, unsigned short* __restrict__ emb_bf,
                      float* __restrict__ enorm, float* __restrict__ loss) {
  int k = blockIdx.x;      // 0..1023
  int c = threadIdx.x;     // 0..255
  if (k == 0 && c == 0) *loss = 0.f;
  float v = emb[(size_t)k * EMB_C + c];
  int kt = k >> 6, g2 = (k >> 4) & 3, lr = k & 15;
  int s = c >> 5, quad = (c >> 3) & 3, j = c & 7;
  size_t chunk = (size_t)kt * 2048 + (size_t)((g2 * 8 + s) * 64 + quad * 16 + lr);
  emb_bf[chunk * 8 + j] = bf16bits(v);
  float sq = v * v;
  for (int m = 32; m; m >>= 1) sq += __shfl_down(sq, m, 64);
  __shared__ float red[4];
  int lane = c & 63, w = c >> 6;
  if (lane == 0) red[w] = sq;
  __syncthreads();
  if (c == 0) enorm[k] = red[0] + red[1] + red[2] + red[3];
}

// ---- staging: one fragment-ordered 64-row tile (32KB), pure linear DMA ----
__device__ __forceinline__ void stage64(const unsigned short* __restrict__ tile_src,
                                        unsigned char* buf, int t) {
#pragma unroll
  for (int j = 0; j < 4; ++j) {
    int d = j * 512 + t;             // chunk 0..2047
    __builtin_amdgcn_global_load_lds(
        (const __attribute__((address_space(1))) void*)(tile_src + (size_t)d * 8),
        (__attribute__((address_space(3))) void*)(buf + (unsigned)(j * 8192 + (t >> 6) * 1024)),
        16, 0, 0);
  }
}

// A-tile swizzle (prologue LDS tile only) — proven R12.
__device__ __forceinline__ int posA(int cc, int nl) {
  return ((cc >> 3) << 3) | ((cc & 7) ^ ((nl ^ (nl >> 2)) & 7));
}

// ================= main kernel: transpose + GEMM + argmin + loss =================
// R17 champion + ONE delta: explicit 16-deep batch-load in the prologue.
// During the prologue af[4][8] (64 VGPR) is not yet live — v16[16] claims
// those registers so all 16 x-loads issue back-to-back (MLP 16/thread) before
// any xn/pack consumption. Theory: prologue was L3-latency-bound at shallow
// MLP (FETCH 34.9MB < 64MB x => x is L3-resident; ~400cyc latency needs
// depth). Everything else byte-identical.
// LDS: [0,128K) bufs 4x32KB (A-tile in bufs 2/3 during prologue) |
//      cjl 4K | keys 1K | xn 1K | xn_p 4K | red
#define LDS_BYTES 141376

__global__ __launch_bounds__(512) void
k_main(const float* __restrict__ x, const unsigned short* __restrict__ embbf,
       const float* __restrict__ enorm, unsigned* __restrict__ keys_g,
       float* __restrict__ loss) {
  extern __shared__ char smem[];
  unsigned char* Abase = (unsigned char*)smem + 65536;  // A-tile in bufs 2/3
  float*    cjl    = (float*)(smem + 131072);          // 1024 f32
  unsigned* keys_l = (unsigned*)(smem + 135168);       // 256 u32
  float*    xn_l   = (float*)(smem + 136192);          // 256 f32
  float*    xn_p   = (float*)(smem + 137216);          // 8 x 128 f32
  float*    red    = (float*)(smem + 141312);          // 16 f32

  int n0 = blockIdx.x * 256;
  int b  = n0 >> 12, hw0 = n0 & 4095;
  int t = threadIdx.x, w = t >> 6, lane = t & 63;
  int quad = lane >> 4, lr = lane & 15;
  int g  = w >> 1;       // n-group 0..3 (64 n)
  int h2 = w & 1;        // k-half (32 k of each 64k tile)

  // B(0)/B(1) staged early: latency hides under the whole prologue
  stage64(embbf,          (unsigned char*)smem,         t);
  stage64(embbf + 16384,  (unsigned char*)smem + 32768, t);

  if (t < 256) keys_l[t] = 0u;
  for (int i = t; i < 1024; i += 512) cjl[i] = 0.375f - 0.5f * enorm[i];
  __syncthreads();

  // ---- prologue: x[c][hw] -> A-tile bf16 (2 passes of 128 n) ----
  bf16x8 af[4][8];
#pragma unroll
  for (int p = 0; p < 2; ++p) {
    if (p) __syncthreads();            // pass-0 af/xn_p reads done before rewrite
    int hwq = t & 31;                  // 4-hw quad -> n-local = hwq*4..+3
    int cg  = t >> 5;                  // c-group 0..15 (16 c each)
    float xn[4] = {0.f, 0.f, 0.f, 0.f};
    {
      const float* xp = x + (size_t)b * (EMB_C * HWB) + hw0 + p * 128 + hwq * 4;
      // R18: batch-issue all 16 loads (64 VGPR, statically indexed -> regs);
      // af isn't live yet so the registers are free. MLP depth 16/thread.
      f32x4 v16[16];
#pragma unroll
      for (int j = 0; j < 16; ++j)
        v16[j] = *(const f32x4*)(xp + (size_t)(cg * 16 + j) * HWB);  // 16B/lane
      unsigned pk[4][8] = {};
#pragma unroll
      for (int j = 0; j < 16; ++j)
#pragma unroll
        for (int m = 0; m < 4; ++m) {
          xn[m] += v16[j][m] * v16[j][m];
          pk[m][j >> 1] |= (unsigned)bf16bits(v16[j][m]) << ((j & 1) * 16);
        }
#pragma unroll
      for (int m = 0; m < 4; ++m) {
        int nl = hwq * 4 + m;
        *(uint4*)(Abase + nl * 512 + posA(cg * 2,     nl) * 16) = *(const uint4*)&pk[m][0];
        *(uint4*)(Abase + nl * 512 + posA(cg * 2 + 1, nl) * 16) = *(const uint4*)&pk[m][4];
      }
    }
    // xn: lanes L and L+32 share nl (cg pair) -> shfl; per-wave partial row
#pragma unroll
    for (int m = 0; m < 4; ++m) xn[m] += __shfl_xor(xn[m], 32, 64);
    if (lane < 32) {
#pragma unroll
      for (int m = 0; m < 4; ++m) xn_p[w * 128 + lane * 4 + m] = xn[m];
    }
    __syncthreads();
    if (t < 128) {                     // reduce 8 wave-partials -> xn_l
      float sum = 0.f;
#pragma unroll
      for (int ww = 0; ww < 8; ++ww) sum += xn_p[ww * 128 + t];
      xn_l[p * 128 + t] = sum;
    }
    if ((g >> 1) == p) {               // n-groups {2p, 2p+1} load af this pass
#pragma unroll
      for (int i = 0; i < 4; ++i) {
        int rA = (g & 1) * 64 + i * 16 + lr;   // local row in this pass's 128
#pragma unroll
        for (int s = 0; s < 8; ++s) {
          int cc = s * 4 + quad;
          af[i][s] = *(const bf16x8*)(Abase + rA * 512 + posA(cc, rA) * 16);
        }
      }
    }
  }
  __syncthreads();   // af complete (drains vmcnt -> bufs 0/1 landed)

  // ---- K-loop: 16 tiles of 64 k; 4-buf rotation, 1 barrier + counted vmcnt ----
  unsigned best[4][4] = {};
  for (int kt = 0; kt < 16; ++kt) {
    if (kt < 14)
      stage64(embbf + (size_t)(kt + 2) * 16384,
              (unsigned char*)smem + (((kt + 2) & 3) << 15), t);
    // outstanding stages: kt,kt+1,kt+2 = 12 chunks -> wait oldest stage (4 each)
    if (kt < 14)       asm volatile("s_waitcnt vmcnt(8)" ::: "memory");
    else if (kt == 14) asm volatile("s_waitcnt vmcnt(4)" ::: "memory");
    else               asm volatile("s_waitcnt vmcnt(0)" ::: "memory");
    __builtin_amdgcn_s_barrier();              // all waves' stage(kt) landed
    __builtin_amdgcn_sched_barrier(0);         // no LDS-read hoist above
    const uint4* sb = (const uint4*)(smem + ((kt & 3) << 15));
    float cj[2]; unsigned kp[2];
#pragma unroll
    for (int j = 0; j < 2; ++j) {
      int k = kt * 64 + h2 * 32 + j * 16 + lr;
      cj[j] = cjl[k];
      kp[j] = 1023u - (unsigned)k;
    }
    f32x4 acc[4][2] = {};
#pragma unroll
    for (int s = 0; s < 8; ++s) {
      bf16x8 bf[2];
#pragma unroll
      for (int j = 0; j < 2; ++j) {
        uint4 q = sb[((h2 * 2 + j) * 8 + s) * 64 + lane];   // conflict-free b128
        bf[j] = __builtin_bit_cast(bf16x8, q);
      }
#pragma unroll
      for (int i = 0; i < 4; ++i)
#pragma unroll
        for (int j = 0; j < 2; ++j)
          acc[i][j] = __builtin_amdgcn_mfma_f32_16x16x32_bf16(af[i][s], bf[j], acc[i][j], 0, 0, 0);
    }
    // fold argmin keys: f = dot + 0.375 - 0.5||e||^2 in (0.04,0.71) -> positive
    // float u32-order-correct; low 10 mantissa bits carry (1023-k).
#pragma unroll
    for (int i = 0; i < 4; ++i)
#pragma unroll
      for (int j = 0; j < 2; ++j)
#pragma unroll
        for (int r = 0; r < 4; ++r) {
          float f = acc[i][j][r] + cj[j];
          unsigned key = (__float_as_uint(f) & 0xFFFFFC00u) | kp[j];
          best[i][r] = best[i][r] > key ? best[i][r] : key;
        }
  }
  __syncthreads();   // k-loop complete before keys_l atomics phase

  // ---- combine keys across k-lanes; k-halves via LDS atomicMax ----
#pragma unroll
  for (int i = 0; i < 4; ++i)
#pragma unroll
    for (int r = 0; r < 4; ++r) {
      unsigned v = best[i][r];
#pragma unroll
      for (int m = 1; m < 16; m <<= 1) {
        unsigned o = (unsigned)__shfl_xor((int)v, m, 64);
        v = v > o ? v : o;
      }
      if (lr == 0) atomicMax(&keys_l[g * 64 + i * 16 + quad * 4 + r], v);
    }
  __syncthreads();

  // ---- keys export + loss partial: d2 = ||x||^2 + 0.75 - 2*f_hat ----
  if (t < 256) {
    unsigned key = keys_l[t];
    keys_g[n0 + t] = key;
    float fh = __uint_as_float(key & 0xFFFFFC00u);
    float lsum = xn_l[t] + 0.75f - 2.0f * fh;
    for (int m = 32; m; m >>= 1) lsum += __shfl_down(lsum, m, 64);
    if (lane == 0) red[w] = lsum;
  }
  __syncthreads();
  if (t == 0)
    atomicAdd(loss, red[0] + red[1] + red[2] + red[3]);   // device-scope
}

// ================= output kernel: gather + transpose + store =================
// 2048 blocks x 256 thr, ~17.3KB LDS -> 8 blocks/CU = 32 waves/CU.
// 16B/lane vector stores; out+1 misalignment absorbed by rotate-by-3 tile
// (stride 68 keeps ds_read_b128 aligned); lane 15 of each 16-lane row group
// peels head (F[0..2]) + tail (F[63]). Loss finalize here.
__global__ __launch_bounds__(256) void
k_out(const float* __restrict__ emb, const unsigned* __restrict__ keys_g,
      const float* __restrict__ loss, float* __restrict__ out) {
  __shared__ float tile[64 * 68];            // 17 KB
  __shared__ int   idx_l[64];
  int e  = blockIdx.x;
  int nt = e >> 1, cH = e & 1;
  int n0 = nt * 64;
  int b  = n0 >> 12, hw0 = n0 & 4095;
  int t = threadIdx.x, w = t >> 6, lane = t & 63;
  if (e == 0 && t == 0)
    out[0] = 1.0625f * (*loss) / 16777216.0f;
  if (t < 64) idx_l[t] = 1023 - (int)(keys_g[n0 + t] & 1023u);
  __syncthreads();
  int nn = t >> 2, ch = t & 3;               // 4 threads per n
  int nrot = (nn - 3) & 63;                  // rotate-by-3 for aligned stores
  const float* er = emb + (size_t)idx_l[nn] * EMB_C + cH * 128;
  float* ob = out + 1 + (size_t)b * (EMB_C * HWB) + (size_t)cH * 128 * HWB + hw0;
  for (int p = 0; p < 2; ++p) {              // 2 passes of 64 c
    if (p) __syncthreads();                  // pass-0 stores done before rewrite
#pragma unroll
    for (int q = 0; q < 4; ++q) {            // 4 lanes x 16B = 64B/line per (nn,q)
      f32x4 v = *(const f32x4*)(er + p * 64 + q * 16 + ch * 4);
#pragma unroll
      for (int m = 0; m < 4; ++m)
        tile[(q * 16 + ch * 4 + m) * 68 + nrot] = v[m];
    }
    __syncthreads();
#pragma unroll
    for (int cc = 0; cc < 4; ++cc) {         // 4 rows per iter x 4 iters = 16/wave
      int cl = w * 16 + cc * 4 + (lane >> 4);
      int i  = lane & 15;                    // 16 lanes per row
      const float* tr = tile + cl * 68;
      float* F = ob + (size_t)(p * 64 + cl) * HWB;
      if (i < 15) {
        f32x4 qv = *(const f32x4*)(tr + 4 * i);      // aligned b128 (68 = 4*17)
        *(f32x4*)(F + 3 + 4 * i) = qv;               // aligned 16B store
      } else {
        F[0] = tr[61]; F[1] = tr[62]; F[2] = tr[63]; // head n=0,1,2
        F[63] = tr[60];                              // tail n=63
      }
    }
  }
}

extern "C" void kernel_launch(void* const* d_in, const int* in_sizes, int n_in,
                              void* d_out, int out_size, void* d_ws, size_t ws_size,
                              hipStream_t stream) {
  const float* x   = (const float*)d_in[0];   // [16,256,64,64]
  const float* emb = (const float*)d_in[1];   // [1024,256]
  float* out = (float*)d_out;                 // [1 + 16777216]
  char*  ws  = (char*)d_ws;

  unsigned short* emb_bf = (unsigned short*)ws;                 // 512 KB (fragment-ordered)
  float*          enorm  = (float*)(ws + 524288);               // 4 KB
  float*          loss   = (float*)(ws + 528384);               // 4 B
  unsigned*       keys_g = (unsigned*)(ws + 532480);            // 256 KB

  hipFuncSetAttribute((const void*)k_main,
                      hipFuncAttributeMaxDynamicSharedMemorySize, LDS_BYTES);

  k_emb <<<dim3(EMB_K),      dim3(EMB_C), 0,         stream>>>(emb, emb_bf, enorm, loss);
  k_main<<<dim3(NPIX / 256), dim3(512),   LDS_BYTES, stream>>>(x, emb_bf, enorm,
                                                               keys_g, loss);
  k_out <<<dim3(NPIX / 32),  dim3(256),   0,         stream>>>(emb, keys_g, loss, out);
}